// Round 5
// baseline (2061.386 us; speedup 1.0000x reference)
//
#include <hip/hip_runtime.h>
#include <hip/hip_bf16.h>

#define HWs 50176      // 224*224
#define WID 224
#define OHW 200704     // 448*448

// ---------------- K0: transpose conv weights OIHW[oc][ic][tap] -> [ic*9+tap][oc]
__global__ void k_wt(const float* __restrict__ w_head, const float* __restrict__ w_blk,
                     float* __restrict__ wt) {
  int l = blockIdx.y;
  int i = blockIdx.x * 256 + threadIdx.x;
  if (i >= 90000) return;
  const float* src = (l == 0) ? w_head : (w_blk + (l - 1) * 90000);
  int oc = i / 900, rem = i - oc * 900;       // rem = ic*9+tap
  wt[l * 90000 + rem * 100 + oc] = src[i];
}

// ---------------- K1: bilinear warp of feat_0/feat_1 + concat into x_in (100 planes fp32)
__global__ void k_warp(const float* __restrict__ f0, const float* __restrict__ f1,
                       const float* __restrict__ fd, const float* __restrict__ fl,
                       float* __restrict__ xin) {
  int p = blockIdx.x * 256 + threadIdx.x;          // 196*256 == 50176 exact
  int y = p / WID, x = p - y * WID;
  float fx0 = fl[p];
  float fy0 = fl[HWs + p];
  float fx1 = fl[2 * HWs + p];
  float fy1 = fl[3 * HWs + p];

  #pragma unroll
  for (int img = 0; img < 2; ++img) {
    const float* src = img ? f1 : f0;
    float fx = img ? fx1 : fx0;
    float fy = img ? fy1 : fy0;
    float px = (float)x + fx, py = (float)y + fy;
    float x0f = floorf(px), y0f = floorf(py);
    float wx = px - x0f, wy = py - y0f;
    int x0 = (int)fminf(fmaxf(x0f,       0.f), 223.f);
    int x1 = (int)fminf(fmaxf(x0f + 1.f, 0.f), 223.f);
    int y0 = (int)fminf(fmaxf(y0f,       0.f), 223.f);
    int y1 = (int)fminf(fmaxf(y0f + 1.f, 0.f), 223.f);
    float w00 = (1.f - wx) * (1.f - wy), w01 = wx * (1.f - wy);
    float w10 = (1.f - wx) * wy,         w11 = wx * wy;
    int i00 = y0 * WID + x0, i01 = y0 * WID + x1;
    int i10 = y1 * WID + x0, i11 = y1 * WID + x1;
    float* dst = xin + img * 32 * HWs;
    for (int c = 0; c < 32; ++c) {
      const float* pl = src + c * HWs;
      dst[c * HWs + p] = w00 * pl[i00] + w01 * pl[i01]
                       + w10 * pl[i10] + w11 * pl[i11];
    }
  }
  for (int c = 0; c < 32; ++c) xin[(64 + c) * HWs + p] = fd[c * HWs + p];
  xin[96 * HWs + p] = fx0; xin[97 * HWs + p] = fy0;
  xin[98 * HWs + p] = fx1; xin[99 * HWs + p] = fy1;
}

// ---------------- K2: GEMM-register-tiled 3x3 conv partial.
// grid (14,23,3): block tile = 16x10 px, all 100 oc; z splits ic 35/35/30.
// 250 active threads: ocg=t/10 (4 oc), pxg=t%10 (row, 16 px). ic chunked by 5.
// LDS: weights chunk 5*9*100 (18KB) + patch 5*12*20 (4.8KB) = 22.8KB.
// Each weight float4 reused across 16 px; each patch value across 4 oc.
__global__ __launch_bounds__(256, 4) void k_conv(
    const float* __restrict__ in, const float* __restrict__ wt,
    float* __restrict__ pbase) {
  __shared__ __align__(16) float wch[4500];        // [icl][tap][100]
  __shared__ __align__(16) float patch[1200];      // [icl][12 rows][stride 20]
  int tid = threadIdx.x;
  int bx = blockIdx.x, by = blockIdx.y, bz = blockIdx.z;
  int icz = (bz == 0) ? 0 : (bz == 1) ? 35 : 70;   // z ic base
  int nic = (bz == 2) ? 30 : 35;
  float* pout = pbase + (size_t)bz * 100 * HWs;

  int ocg = tid / 10, pxg = tid - ocg * 10;        // valid for tid<250
  int row = by * 10 + pxg;
  int col0 = bx * 16;

  float acc[4][16];
  #pragma unroll
  for (int o = 0; o < 4; ++o)
    #pragma unroll
    for (int p = 0; p < 16; ++p) acc[o][p] = 0.f;

  for (int ic0 = 0; ic0 < nic; ic0 += 5) {
    int n = (nic - ic0 < 5) ? (nic - ic0) : 5;
    // stage weights: contiguous slice of wt
    const float* wsrc = wt + (icz + ic0) * 900;
    int nw = n * 900;
    for (int j = tid; j < nw; j += 256) wch[j] = wsrc[j];
    // stage patch: n ic x 12 rows x 18 cols (stride 20)
    int np = n * 216;
    for (int j = tid; j < np; j += 256) {
      int icl = j / 216, r = j - icl * 216;
      int ry = r / 18, rx = r - ry * 18;
      int gy = by * 10 - 1 + ry, gx = col0 - 1 + rx;
      float v = 0.f;
      if ((unsigned)gy < 224u && (unsigned)gx < 224u)
        v = in[(icz + ic0 + icl) * HWs + gy * WID + gx];
      patch[(icl * 12 + ry) * 20 + rx] = v;
    }
    __syncthreads();

    if (tid < 250) {
      for (int icl = 0; icl < n; ++icl) {
        #pragma unroll
        for (int dy = 0; dy < 3; ++dy) {
          const float* prow = &patch[(icl * 12 + pxg + dy) * 20];
          float r[18];
          #pragma unroll
          for (int q = 0; q < 4; ++q) {
            float4 t4 = *(const float4*)(prow + 4 * q);
            r[4*q] = t4.x; r[4*q+1] = t4.y; r[4*q+2] = t4.z; r[4*q+3] = t4.w;
          }
          { float2 t2 = *(const float2*)(prow + 16); r[16] = t2.x; r[17] = t2.y; }
          #pragma unroll
          for (int dx = 0; dx < 3; ++dx) {
            float4 w4 = *(const float4*)&wch[(icl * 9 + dy * 3 + dx) * 100 + 4 * ocg];
            #pragma unroll
            for (int p = 0; p < 16; ++p) {
              acc[0][p] = fmaf(w4.x, r[dx + p], acc[0][p]);
              acc[1][p] = fmaf(w4.y, r[dx + p], acc[1][p]);
              acc[2][p] = fmaf(w4.z, r[dx + p], acc[2][p]);
              acc[3][p] = fmaf(w4.w, r[dx + p], acc[3][p]);
            }
          }
        }
      }
    }
    __syncthreads();
  }

  if (tid < 250 && row < 224) {
    #pragma unroll
    for (int o = 0; o < 4; ++o) {
      float* dst = pout + (4 * ocg + o) * HWs + row * WID + col0;
      #pragma unroll
      for (int q = 0; q < 4; ++q)
        *(float4*)(dst + 4 * q) = make_float4(acc[o][4*q], acc[o][4*q+1],
                                              acc[o][4*q+2], acc[o][4*q+3]);
    }
  }
}

// ---------------- K3: fused 3-partial combine + PReLU*mask + activation write
//                      + incremental einsum accumulate into xlast.
__global__ void k_post(const float* __restrict__ pA, const float* __restrict__ pB,
                       const float* __restrict__ pC,
                       const float* __restrict__ avec, const float* __restrict__ mask,
                       const float* __restrict__ wlast, const float* __restrict__ blast,
                       float* __restrict__ xact, float* __restrict__ xlast,
                       int base, int init) {
  __shared__ __align__(16) float wl[100 * 36];     // [il][o], 14.4KB
  __shared__ float al[100];
  int tid = threadIdx.x;
  for (int j = tid; j < 100 * 36; j += 256) {
    int il = j / 36, o = j - il * 36;
    wl[j] = wlast[o * 500 + base + il];
  }
  if (tid < 100) al[tid] = avec[tid];
  __syncthreads();
  int p = blockIdx.x * 256 + tid;
  float m = mask[p];
  float acc[36];
  #pragma unroll
  for (int o = 0; o < 36; ++o) acc[o] = init ? blast[o] : xlast[o * HWs + p];
  for (int oc = 0; oc < 100; ++oc) {
    float z = pA[oc * HWs + p] + pB[oc * HWs + p] + pC[oc * HWs + p];
    float v = (z >= 0.f ? z : al[oc] * z) * m;
    xact[oc * HWs + p] = v;
    const float4* wp = (const float4*)&wl[oc * 36];
    #pragma unroll
    for (int j = 0; j < 9; ++j) {
      float4 t = wp[j];
      acc[4*j]   += t.x * v;
      acc[4*j+1] += t.y * v;
      acc[4*j+2] += t.z * v;
      acc[4*j+3] += t.w * v;
    }
  }
  #pragma unroll
  for (int o = 0; o < 36; ++o) xlast[o * HWs + p] = acc[o];
}

// ---------------- K4: smn = conv3x3(xlast[4:36], w_mask) + b_mask (2 ch), fp64 accum
__global__ void k_smn(const float* __restrict__ xlast, const float* __restrict__ wmask,
                      const float* __restrict__ bmask, float* __restrict__ smn) {
  __shared__ float wm[576];
  int tid = threadIdx.x;
  for (int j = tid; j < 576; j += 256) wm[j] = wmask[j];
  __syncthreads();
  int p = blockIdx.x * 256 + tid;
  int y = p / WID, x = p - y * WID;
  double a0 = 0.0, a1 = 0.0;
  for (int ic = 0; ic < 32; ++ic) {
    const float* pl = xlast + (4 + ic) * HWs;
    #pragma unroll
    for (int dy = -1; dy <= 1; ++dy) {
      int gy = y + dy;
      if ((unsigned)gy < 224u) {
        #pragma unroll
        for (int dx = -1; dx <= 1; ++dx) {
          int gx = x + dx;
          if ((unsigned)gx < 224u) {
            double v = (double)pl[gy * WID + gx];
            int t = (dy + 1) * 3 + (dx + 1);
            a0 += (double)wm[ic * 9 + t] * v;        // oc 0
            a1 += (double)wm[288 + ic * 9 + t] * v;  // oc 1
          }
        }
      }
    }
  }
  smn[p]       = (float)(a0 + (double)bmask[0]);
  smn[HWs + p] = (float)(a1 + (double)bmask[1]);
}

// ---------------- K5: 2x bilinear upsample (jax.image.resize 'linear') + mask compare
__global__ void k_upsample(const float* __restrict__ xlast, const float* __restrict__ smn,
                           const float* __restrict__ smask, float* __restrict__ out) {
  int q = blockIdx.x * 256 + threadIdx.x;          // 784*256 == 200704 exact
  int oy = q / 448, ox = q - oy * 448;
  int ky = oy >> 1, kx = ox >> 1;
  int r0, r1, c0, c1; float wy0, wy1, wx0, wx1;
  if (oy & 1) { r0 = ky; r1 = (ky < 223) ? ky + 1 : 223; wy0 = 0.75f; wy1 = 0.25f; }
  else        { r0 = (ky > 0) ? ky - 1 : 0; r1 = ky;     wy0 = 0.25f; wy1 = 0.75f; }
  if (ox & 1) { c0 = kx; c1 = (kx < 223) ? kx + 1 : 223; wx0 = 0.75f; wx1 = 0.25f; }
  else        { c0 = (kx > 0) ? kx - 1 : 0; c1 = kx;     wx0 = 0.25f; wx1 = 0.75f; }
  float w00 = wy0 * wx0, w01 = wy0 * wx1, w10 = wy1 * wx0, w11 = wy1 * wx1;
  int i00 = r0 * WID + c0, i01 = r0 * WID + c1, i10 = r1 * WID + c0, i11 = r1 * WID + c1;
  for (int ch = 0; ch < 36; ++ch) {
    const float* pl = xlast + ch * HWs;
    out[ch * OHW + q] = w00 * pl[i00] + w01 * pl[i01] + w10 * pl[i10] + w11 * pl[i11];
  }
  double s0 = (double)w00 * smn[i00] + (double)w01 * smn[i01]
            + (double)w10 * smn[i10] + (double)w11 * smn[i11];
  const float* s1p = smn + HWs;
  double s1 = (double)w00 * s1p[i00] + (double)w01 * s1p[i01]
            + (double)w10 * s1p[i10] + (double)w11 * s1p[i11];
  float mu = smask[ky * WID + kx];
  out[36 * OHW + q] = (s0 > s1) ? mu : 0.f;
}

extern "C" void kernel_launch(void* const* d_in, const int* in_sizes, int n_in,
                              void* d_out, int out_size, void* d_ws, size_t ws_size,
                              hipStream_t stream) {
  const float* feat0   = (const float*)d_in[0];
  const float* feat1   = (const float*)d_in[1];
  const float* featd   = (const float*)d_in[2];
  const float* flow    = (const float*)d_in[3];
  const float* smask   = (const float*)d_in[4];
  const float* w_head  = (const float*)d_in[5];
  const float* a_head  = (const float*)d_in[6];
  const float* w_blk   = (const float*)d_in[7];
  const float* a_blk   = (const float*)d_in[8];
  const float* w_last  = (const float*)d_in[9];
  const float* b_last  = (const float*)d_in[10];
  const float* w_mask  = (const float*)d_in[11];
  const float* b_mask  = (const float*)d_in[12];

  // ws layout: act0/act1 + partials pA/pB/pC + xlast + smn + wt (~110 MB)
  float* act0  = (float*)d_ws;            // 100 planes
  float* act1  = act0 + 100 * HWs;        // 100 planes
  float* pA    = act1 + 100 * HWs;        // 100 planes
  float* pB    = pA   + 100 * HWs;        // 100 planes
  float* pC    = pB   + 100 * HWs;        // 100 planes
  float* xlast = pC   + 100 * HWs;        // 36 planes
  float* smn   = xlast + 36 * HWs;        // 2 planes
  float* wt    = smn + 2 * HWs;           // 5*90000 floats

  k_wt<<<dim3(352, 5), 256, 0, stream>>>(w_head, w_blk, wt);
  k_warp<<<196, 256, 0, stream>>>(feat0, feat1, featd, flow, act0);

  dim3 cgrid(14, 23, 3);
  // head: act0 -> partials -> act1, einsum slice 0 (init)
  k_conv<<<cgrid, 256, 0, stream>>>(act0, wt, pA);
  k_post<<<196, 256, 0, stream>>>(pA, pB, pC, a_head, smask, w_last, b_last,
                                  act1, xlast, 0, 1);
  // blocks: ping-pong act1 <-> act0
  float* src = act1; float* dst = act0;
  for (int l = 0; l < 4; ++l) {
    k_conv<<<cgrid, 256, 0, stream>>>(src, wt + (l + 1) * 90000, pA);
    k_post<<<196, 256, 0, stream>>>(pA, pB, pC, a_blk + l * 100, smask, w_last, b_last,
                                    dst, xlast, (l + 1) * 100, 0);
    float* t = src; src = dst; dst = t;
  }

  k_smn<<<196, 256, 0, stream>>>(xlast, w_mask, b_mask, smn);
  k_upsample<<<784, 256, 0, stream>>>(xlast, smn, smask, (float*)d_out);
}

// Round 6
// 1123.823 us; speedup vs baseline: 1.8343x; 1.8343x over previous
//
#include <hip/hip_runtime.h>
#include <hip/hip_bf16.h>

#define HWs 50176      // 224*224
#define WID 224
#define OHW 200704     // 448*448

// ---------------- K0: transpose conv weights OIHW[oc][ic][tap] -> [ic*9+tap][oc]
__global__ void k_wt(const float* __restrict__ w_head, const float* __restrict__ w_blk,
                     float* __restrict__ wt) {
  int l = blockIdx.y;
  int i = blockIdx.x * 256 + threadIdx.x;
  if (i >= 90000) return;
  const float* src = (l == 0) ? w_head : (w_blk + (l - 1) * 90000);
  int oc = i / 900, rem = i - oc * 900;       // rem = ic*9+tap
  wt[l * 90000 + rem * 100 + oc] = src[i];
}

// ---------------- K1: bilinear warp of feat_0/feat_1 + concat into x_in (100 planes fp32)
__global__ void k_warp(const float* __restrict__ f0, const float* __restrict__ f1,
                       const float* __restrict__ fd, const float* __restrict__ fl,
                       float* __restrict__ xin) {
  int p = blockIdx.x * 256 + threadIdx.x;          // 196*256 == 50176 exact
  int y = p / WID, x = p - y * WID;
  float fx0 = fl[p];
  float fy0 = fl[HWs + p];
  float fx1 = fl[2 * HWs + p];
  float fy1 = fl[3 * HWs + p];

  #pragma unroll
  for (int img = 0; img < 2; ++img) {
    const float* src = img ? f1 : f0;
    float fx = img ? fx1 : fx0;
    float fy = img ? fy1 : fy0;
    float px = (float)x + fx, py = (float)y + fy;
    float x0f = floorf(px), y0f = floorf(py);
    float wx = px - x0f, wy = py - y0f;
    int x0 = (int)fminf(fmaxf(x0f,       0.f), 223.f);
    int x1 = (int)fminf(fmaxf(x0f + 1.f, 0.f), 223.f);
    int y0 = (int)fminf(fmaxf(y0f,       0.f), 223.f);
    int y1 = (int)fminf(fmaxf(y0f + 1.f, 0.f), 223.f);
    float w00 = (1.f - wx) * (1.f - wy), w01 = wx * (1.f - wy);
    float w10 = (1.f - wx) * wy,         w11 = wx * wy;
    int i00 = y0 * WID + x0, i01 = y0 * WID + x1;
    int i10 = y1 * WID + x0, i11 = y1 * WID + x1;
    float* dst = xin + img * 32 * HWs;
    for (int c = 0; c < 32; ++c) {
      const float* pl = src + c * HWs;
      dst[c * HWs + p] = w00 * pl[i00] + w01 * pl[i01]
                       + w10 * pl[i10] + w11 * pl[i11];
    }
  }
  for (int c = 0; c < 32; ++c) xin[(64 + c) * HWs + p] = fd[c * HWs + p];
  xin[96 * HWs + p] = fx0; xin[97 * HWs + p] = fy0;
  xin[98 * HWs + p] = fx1; xin[99 * HWs + p] = fy1;
}

// ---------------- K2: GEMM-register-tiled 3x3 conv partial.
// grid (7,45,3): block tile = 32 cols x 5 rows, all 100 oc; z splits ic 34/33/33.
// 250 active threads: ocg=tid/10 (4 oc); rem=tid%10: colg=rem&1 (16-col half),
// rowl=rem>>1 (row). Lane pairs (colg 0/1) cover a full 128B line on store.
// ic chunked by 5. LDS: weights 5*900 (18KB) + patch 5*7*36 (5KB) = 23KB.
// Each weight float4 reused over 16 px; each patch value over 4 oc; 64 indep FMA chains.
__global__ __launch_bounds__(256) void k_conv(
    const float* __restrict__ in, const float* __restrict__ wt,
    float* __restrict__ pbase) {
  __shared__ __align__(16) float wch[4500];        // [icl][tap][100]
  __shared__ __align__(16) float patch[1260];      // [icl][7 rows][stride 36]
  int tid = threadIdx.x;
  int bx = blockIdx.x, by = blockIdx.y, bz = blockIdx.z;
  int icz = (bz == 0) ? 0 : (bz == 1) ? 34 : 67;
  int nic = (bz == 0) ? 34 : 33;
  float* pout = pbase + (size_t)bz * 100 * HWs;

  int ocg = tid / 10, rem = tid - ocg * 10;        // valid for tid<250
  int colg = rem & 1, rowl = rem >> 1;
  int row = by * 5 + rowl;
  int col0 = bx * 32 + colg * 16;

  float acc[4][16];
  #pragma unroll
  for (int o = 0; o < 4; ++o)
    #pragma unroll
    for (int p = 0; p < 16; ++p) acc[o][p] = 0.f;

  for (int ic0 = 0; ic0 < nic; ic0 += 5) {
    int n = (nic - ic0 < 5) ? (nic - ic0) : 5;
    // stage weights: contiguous slice of wt
    const float* wsrc = wt + (size_t)(icz + ic0) * 900;
    int nw = n * 900;
    __syncthreads();
    for (int j = tid; j < nw; j += 256) wch[j] = wsrc[j];
    // stage patch: n ic x 7 rows x 34 cols (stride 36)
    int np = n * 238;                              // 7*34
    for (int j = tid; j < np; j += 256) {
      int icl = j / 238, r = j - icl * 238;
      int ry = r / 34, rx = r - ry * 34;
      int gy = by * 5 - 1 + ry, gx = bx * 32 - 1 + rx;
      float v = 0.f;
      if ((unsigned)gy < 224u && (unsigned)gx < 224u)
        v = in[(icz + ic0 + icl) * HWs + gy * WID + gx];
      patch[icl * 252 + ry * 36 + rx] = v;
    }
    __syncthreads();

    if (tid < 250) {
      for (int icl = 0; icl < n; ++icl) {
        #pragma unroll
        for (int dy = 0; dy < 3; ++dy) {
          const float* prow = &patch[icl * 252 + (rowl + dy) * 36 + colg * 16];
          float r[18];
          #pragma unroll
          for (int q = 0; q < 4; ++q) {
            float4 t4 = *(const float4*)(prow + 4 * q);
            r[4*q] = t4.x; r[4*q+1] = t4.y; r[4*q+2] = t4.z; r[4*q+3] = t4.w;
          }
          { float2 t2 = *(const float2*)(prow + 16); r[16] = t2.x; r[17] = t2.y; }
          #pragma unroll
          for (int dx = 0; dx < 3; ++dx) {
            float4 w4 = *(const float4*)&wch[(icl * 9 + dy * 3 + dx) * 100 + 4 * ocg];
            #pragma unroll
            for (int p = 0; p < 16; ++p) {
              acc[0][p] = fmaf(w4.x, r[dx + p], acc[0][p]);
              acc[1][p] = fmaf(w4.y, r[dx + p], acc[1][p]);
              acc[2][p] = fmaf(w4.z, r[dx + p], acc[2][p]);
              acc[3][p] = fmaf(w4.w, r[dx + p], acc[3][p]);
            }
          }
        }
      }
    }
  }

  if (tid < 250 && row < 224) {
    #pragma unroll
    for (int o = 0; o < 4; ++o) {
      float* dst = pout + (size_t)(4 * ocg + o) * HWs + row * WID + col0;
      #pragma unroll
      for (int q = 0; q < 4; ++q)
        *(float4*)(dst + 4 * q) = make_float4(acc[o][4*q], acc[o][4*q+1],
                                              acc[o][4*q+2], acc[o][4*q+3]);
    }
  }
}

// ---------------- K3: fused 3-partial combine + PReLU*mask + activation write
//                      + incremental einsum accumulate into xlast.
__global__ void k_post(const float* __restrict__ pA, const float* __restrict__ pB,
                       const float* __restrict__ pC,
                       const float* __restrict__ avec, const float* __restrict__ mask,
                       const float* __restrict__ wlast, const float* __restrict__ blast,
                       float* __restrict__ xact, float* __restrict__ xlast,
                       int base, int init) {
  __shared__ __align__(16) float wl[100 * 36];     // [il][o], 14.4KB
  __shared__ float al[100];
  int tid = threadIdx.x;
  for (int j = tid; j < 100 * 36; j += 256) {
    int il = j / 36, o = j - il * 36;
    wl[j] = wlast[o * 500 + base + il];
  }
  if (tid < 100) al[tid] = avec[tid];
  __syncthreads();
  int p = blockIdx.x * 256 + tid;
  float m = mask[p];
  float acc[36];
  #pragma unroll
  for (int o = 0; o < 36; ++o) acc[o] = init ? blast[o] : xlast[o * HWs + p];
  for (int oc = 0; oc < 100; ++oc) {
    float z = pA[oc * HWs + p] + pB[oc * HWs + p] + pC[oc * HWs + p];
    float v = (z >= 0.f ? z : al[oc] * z) * m;
    xact[oc * HWs + p] = v;
    const float4* wp = (const float4*)&wl[oc * 36];
    #pragma unroll
    for (int j = 0; j < 9; ++j) {
      float4 t = wp[j];
      acc[4*j]   += t.x * v;
      acc[4*j+1] += t.y * v;
      acc[4*j+2] += t.z * v;
      acc[4*j+3] += t.w * v;
    }
  }
  #pragma unroll
  for (int o = 0; o < 36; ++o) xlast[o * HWs + p] = acc[o];
}

// ---------------- K4: smn = conv3x3(xlast[4:36], w_mask) + b_mask (2 ch), fp64 accum
__global__ void k_smn(const float* __restrict__ xlast, const float* __restrict__ wmask,
                      const float* __restrict__ bmask, float* __restrict__ smn) {
  __shared__ float wm[576];
  int tid = threadIdx.x;
  for (int j = tid; j < 576; j += 256) wm[j] = wmask[j];
  __syncthreads();
  int p = blockIdx.x * 256 + tid;
  int y = p / WID, x = p - y * WID;
  double a0 = 0.0, a1 = 0.0;
  for (int ic = 0; ic < 32; ++ic) {
    const float* pl = xlast + (4 + ic) * HWs;
    #pragma unroll
    for (int dy = -1; dy <= 1; ++dy) {
      int gy = y + dy;
      if ((unsigned)gy < 224u) {
        #pragma unroll
        for (int dx = -1; dx <= 1; ++dx) {
          int gx = x + dx;
          if ((unsigned)gx < 224u) {
            double v = (double)pl[gy * WID + gx];
            int t = (dy + 1) * 3 + (dx + 1);
            a0 += (double)wm[ic * 9 + t] * v;        // oc 0
            a1 += (double)wm[288 + ic * 9 + t] * v;  // oc 1
          }
        }
      }
    }
  }
  smn[p]       = (float)(a0 + (double)bmask[0]);
  smn[HWs + p] = (float)(a1 + (double)bmask[1]);
}

// ---------------- K5: 2x bilinear upsample (jax.image.resize 'linear') + mask compare
__global__ void k_upsample(const float* __restrict__ xlast, const float* __restrict__ smn,
                           const float* __restrict__ smask, float* __restrict__ out) {
  int q = blockIdx.x * 256 + threadIdx.x;          // 784*256 == 200704 exact
  int oy = q / 448, ox = q - oy * 448;
  int ky = oy >> 1, kx = ox >> 1;
  int r0, r1, c0, c1; float wy0, wy1, wx0, wx1;
  if (oy & 1) { r0 = ky; r1 = (ky < 223) ? ky + 1 : 223; wy0 = 0.75f; wy1 = 0.25f; }
  else        { r0 = (ky > 0) ? ky - 1 : 0; r1 = ky;     wy0 = 0.25f; wy1 = 0.75f; }
  if (ox & 1) { c0 = kx; c1 = (kx < 223) ? kx + 1 : 223; wx0 = 0.75f; wx1 = 0.25f; }
  else        { c0 = (kx > 0) ? kx - 1 : 0; c1 = kx;     wx0 = 0.25f; wx1 = 0.75f; }
  float w00 = wy0 * wx0, w01 = wy0 * wx1, w10 = wy1 * wx0, w11 = wy1 * wx1;
  int i00 = r0 * WID + c0, i01 = r0 * WID + c1, i10 = r1 * WID + c0, i11 = r1 * WID + c1;
  for (int ch = 0; ch < 36; ++ch) {
    const float* pl = xlast + ch * HWs;
    out[ch * OHW + q] = w00 * pl[i00] + w01 * pl[i01] + w10 * pl[i10] + w11 * pl[i11];
  }
  double s0 = (double)w00 * smn[i00] + (double)w01 * smn[i01]
            + (double)w10 * smn[i10] + (double)w11 * smn[i11];
  const float* s1p = smn + HWs;
  double s1 = (double)w00 * s1p[i00] + (double)w01 * s1p[i01]
            + (double)w10 * s1p[i10] + (double)w11 * s1p[i11];
  float mu = smask[ky * WID + kx];
  out[36 * OHW + q] = (s0 > s1) ? mu : 0.f;
}

extern "C" void kernel_launch(void* const* d_in, const int* in_sizes, int n_in,
                              void* d_out, int out_size, void* d_ws, size_t ws_size,
                              hipStream_t stream) {
  const float* feat0   = (const float*)d_in[0];
  const float* feat1   = (const float*)d_in[1];
  const float* featd   = (const float*)d_in[2];
  const float* flow    = (const float*)d_in[3];
  const float* smask   = (const float*)d_in[4];
  const float* w_head  = (const float*)d_in[5];
  const float* a_head  = (const float*)d_in[6];
  const float* w_blk   = (const float*)d_in[7];
  const float* a_blk   = (const float*)d_in[8];
  const float* w_last  = (const float*)d_in[9];
  const float* b_last  = (const float*)d_in[10];
  const float* w_mask  = (const float*)d_in[11];
  const float* b_mask  = (const float*)d_in[12];

  // ws layout: act0/act1 + partials pA/pB/pC + xlast + smn + wt (~110 MB)
  float* act0  = (float*)d_ws;            // 100 planes
  float* act1  = act0 + 100 * HWs;        // 100 planes
  float* pA    = act1 + 100 * HWs;        // 100 planes
  float* pB    = pA   + 100 * HWs;        // 100 planes
  float* pC    = pB   + 100 * HWs;        // 100 planes
  float* xlast = pC   + 100 * HWs;        // 36 planes
  float* smn   = xlast + 36 * HWs;        // 2 planes
  float* wt    = smn + 2 * HWs;           // 5*90000 floats

  k_wt<<<dim3(352, 5), 256, 0, stream>>>(w_head, w_blk, wt);
  k_warp<<<196, 256, 0, stream>>>(feat0, feat1, featd, flow, act0);

  dim3 cgrid(7, 45, 3);
  // head: act0 -> partials -> act1, einsum slice 0 (init)
  k_conv<<<cgrid, 256, 0, stream>>>(act0, wt, pA);
  k_post<<<196, 256, 0, stream>>>(pA, pB, pC, a_head, smask, w_last, b_last,
                                  act1, xlast, 0, 1);
  // blocks: ping-pong act1 <-> act0
  float* src = act1; float* dst = act0;
  for (int l = 0; l < 4; ++l) {
    k_conv<<<cgrid, 256, 0, stream>>>(src, wt + (l + 1) * 90000, pA);
    k_post<<<196, 256, 0, stream>>>(pA, pB, pC, a_blk + l * 100, smask, w_last, b_last,
                                    dst, xlast, (l + 1) * 100, 0);
    float* t = src; src = dst; dst = t;
  }

  k_smn<<<196, 256, 0, stream>>>(xlast, w_mask, b_mask, smn);
  k_upsample<<<784, 256, 0, stream>>>(xlast, smn, smask, (float*)d_out);
}

// Round 7
// 1016.317 us; speedup vs baseline: 2.0283x; 1.1058x over previous
//
#include <hip/hip_runtime.h>
#include <hip/hip_bf16.h>

#define HWs 50176      // 224*224
#define WID 224
#define OHW 200704     // 448*448

// ---------------- K0: transpose conv weights OIHW[oc][ic][tap] -> [ic*9+tap][oc]
__global__ void k_wt(const float* __restrict__ w_head, const float* __restrict__ w_blk,
                     float* __restrict__ wt) {
  int l = blockIdx.y;
  int i = blockIdx.x * 256 + threadIdx.x;
  if (i >= 90000) return;
  const float* src = (l == 0) ? w_head : (w_blk + (l - 1) * 90000);
  int oc = i / 900, rem = i - oc * 900;       // rem = ic*9+tap
  wt[l * 90000 + rem * 100 + oc] = src[i];
}

// ---------------- K0b: xlast = b_last (re-init every launch; k_post atomically accumulates)
__global__ void k_binit(const float* __restrict__ blast, float* __restrict__ xlast) {
  int p = blockIdx.x * 256 + threadIdx.x;
  xlast[(size_t)blockIdx.y * HWs + p] = blast[blockIdx.y];
}

// ---------------- K1: bilinear warp + concat, channel-split for occupancy.
// grid (196,4) x 256: y-quarter handles 8 ch of f0w, 8 of f1w, 8 of fd; y==0 also flow.
__global__ void k_warp(const float* __restrict__ f0, const float* __restrict__ f1,
                       const float* __restrict__ fd, const float* __restrict__ fl,
                       float* __restrict__ xin) {
  int p = blockIdx.x * 256 + threadIdx.x;
  int yq = blockIdx.y;
  int y = p / WID, x = p - y * WID;
  float fx0 = fl[p];
  float fy0 = fl[HWs + p];
  float fx1 = fl[2 * HWs + p];
  float fy1 = fl[3 * HWs + p];

  #pragma unroll
  for (int img = 0; img < 2; ++img) {
    const float* src = img ? f1 : f0;
    float fx = img ? fx1 : fx0;
    float fy = img ? fy1 : fy0;
    float px = (float)x + fx, py = (float)y + fy;
    float x0f = floorf(px), y0f = floorf(py);
    float wx = px - x0f, wy = py - y0f;
    int x0 = (int)fminf(fmaxf(x0f,       0.f), 223.f);
    int x1 = (int)fminf(fmaxf(x0f + 1.f, 0.f), 223.f);
    int y0 = (int)fminf(fmaxf(y0f,       0.f), 223.f);
    int y1 = (int)fminf(fmaxf(y0f + 1.f, 0.f), 223.f);
    float w00 = (1.f - wx) * (1.f - wy), w01 = wx * (1.f - wy);
    float w10 = (1.f - wx) * wy,         w11 = wx * wy;
    int i00 = y0 * WID + x0, i01 = y0 * WID + x1;
    int i10 = y1 * WID + x0, i11 = y1 * WID + x1;
    float* dst = xin + img * 32 * HWs;
    for (int c = yq * 8; c < yq * 8 + 8; ++c) {
      const float* pl = src + c * HWs;
      dst[c * HWs + p] = w00 * pl[i00] + w01 * pl[i01]
                       + w10 * pl[i10] + w11 * pl[i11];
    }
  }
  for (int c = yq * 8; c < yq * 8 + 8; ++c)
    xin[(64 + c) * HWs + p] = fd[c * HWs + p];
  if (yq == 0) {
    xin[96 * HWs + p] = fx0; xin[97 * HWs + p] = fy0;
    xin[98 * HWs + p] = fx1; xin[99 * HWs + p] = fy1;
  }
}

// ---------------- K2: GEMM-register-tiled 3x3 conv partial.
// grid (14,45,3): block tile = 16 cols x 5 rows, all 100 oc; z splits ic 34/33/33.
// 1890 blocks (~7/CU). 250 active threads: ocg=tid/10 (4 oc); rem=tid%10:
// colg=rem&1 (8-col half), rowl=rem>>1 (row). ic chunked by 5.
// LDS: weights 4500 (18KB) + patch 5*7*20 (2.8KB) = 20.8KB -> ~7 blocks/CU.
// Each weight float4 reused over 8 px; each patch value over 4 oc; 32 indep FMA chains.
__global__ __launch_bounds__(256) void k_conv(
    const float* __restrict__ in, const float* __restrict__ wt,
    float* __restrict__ pbase) {
  __shared__ __align__(16) float wch[4500];        // [icl][tap][100]
  __shared__ __align__(16) float patch[700];       // [icl][7 rows][stride 20]
  int tid = threadIdx.x;
  int bx = blockIdx.x, by = blockIdx.y, bz = blockIdx.z;
  int icz = (bz == 0) ? 0 : (bz == 1) ? 34 : 67;
  int nic = (bz == 0) ? 34 : 33;
  float* pout = pbase + (size_t)bz * 100 * HWs;

  int ocg = tid / 10, rem = tid - ocg * 10;        // valid for tid<250
  int colg = rem & 1, rowl = rem >> 1;
  int row = by * 5 + rowl;
  int col0 = bx * 16 + colg * 8;

  float acc[4][8];
  #pragma unroll
  for (int o = 0; o < 4; ++o)
    #pragma unroll
    for (int p = 0; p < 8; ++p) acc[o][p] = 0.f;

  for (int ic0 = 0; ic0 < nic; ic0 += 5) {
    int n = (nic - ic0 < 5) ? (nic - ic0) : 5;
    const float* wsrc = wt + (size_t)(icz + ic0) * 900;
    int nw = n * 900;
    __syncthreads();
    for (int j = tid; j < nw; j += 256) wch[j] = wsrc[j];
    int np = n * 126;                              // 7 rows * 18 cols
    for (int j = tid; j < np; j += 256) {
      int icl = j / 126, r = j - icl * 126;
      int ry = r / 18, rx = r - ry * 18;
      int gy = by * 5 - 1 + ry, gx = bx * 16 - 1 + rx;
      float v = 0.f;
      if ((unsigned)gy < 224u && (unsigned)gx < 224u)
        v = in[(icz + ic0 + icl) * HWs + gy * WID + gx];
      patch[icl * 140 + ry * 20 + rx] = v;
    }
    __syncthreads();

    if (tid < 250) {
      for (int icl = 0; icl < n; ++icl) {
        #pragma unroll
        for (int dy = 0; dy < 3; ++dy) {
          const float* prow = &patch[icl * 140 + (rowl + dy) * 20 + colg * 8];
          float r[10];
          #pragma unroll
          for (int q = 0; q < 2; ++q) {
            float4 t4 = *(const float4*)(prow + 4 * q);
            r[4*q] = t4.x; r[4*q+1] = t4.y; r[4*q+2] = t4.z; r[4*q+3] = t4.w;
          }
          { float2 t2 = *(const float2*)(prow + 8); r[8] = t2.x; r[9] = t2.y; }
          #pragma unroll
          for (int dx = 0; dx < 3; ++dx) {
            float4 w4 = *(const float4*)&wch[(icl * 9 + dy * 3 + dx) * 100 + 4 * ocg];
            #pragma unroll
            for (int p = 0; p < 8; ++p) {
              acc[0][p] = fmaf(w4.x, r[dx + p], acc[0][p]);
              acc[1][p] = fmaf(w4.y, r[dx + p], acc[1][p]);
              acc[2][p] = fmaf(w4.z, r[dx + p], acc[2][p]);
              acc[3][p] = fmaf(w4.w, r[dx + p], acc[3][p]);
            }
          }
        }
      }
    }
  }

  if (tid < 250 && row < 224) {
    #pragma unroll
    for (int o = 0; o < 4; ++o) {
      float* dst = pout + (size_t)(4 * ocg + o) * HWs + row * WID + col0;
      *(float4*)(dst)     = make_float4(acc[o][0], acc[o][1], acc[o][2], acc[o][3]);
      *(float4*)(dst + 4) = make_float4(acc[o][4], acc[o][5], acc[o][6], acc[o][7]);
    }
  }
}

// ---------------- K3: fused 3-partial combine + PReLU*mask + activation write
// + einsum contribution via atomicAdd into xlast (seeded with b_last by k_binit).
// grid (784, 4) x 64 threads: y picks 25-oc slice -> 3136 blocks (~12 waves/CU).
__global__ void k_post(const float* __restrict__ pA, const float* __restrict__ pB,
                       const float* __restrict__ pC,
                       const float* __restrict__ avec, const float* __restrict__ mask,
                       const float* __restrict__ wlast,
                       float* __restrict__ xact, float* __restrict__ xlast,
                       int base) {
  __shared__ __align__(16) float wl[25 * 36];      // [il][o] for this slice
  __shared__ float al[25];
  int tid = threadIdx.x;
  int ocq = blockIdx.y;
  for (int j = tid; j < 25 * 36; j += 64) {
    int il = j / 36, o = j - il * 36;
    wl[j] = wlast[o * 500 + base + 25 * ocq + il];
  }
  if (tid < 25) al[tid] = avec[25 * ocq + tid];
  __syncthreads();
  int p = blockIdx.x * 64 + tid;
  float m = mask[p];
  float acc[36];
  #pragma unroll
  for (int o = 0; o < 36; ++o) acc[o] = 0.f;
  for (int il = 0; il < 25; ++il) {
    int oc = 25 * ocq + il;
    float z = pA[oc * HWs + p] + pB[oc * HWs + p] + pC[oc * HWs + p];
    float v = (z >= 0.f ? z : al[il] * z) * m;
    xact[oc * HWs + p] = v;
    const float4* wp = (const float4*)&wl[il * 36];
    #pragma unroll
    for (int j = 0; j < 9; ++j) {
      float4 t = wp[j];
      acc[4*j]   += t.x * v;
      acc[4*j+1] += t.y * v;
      acc[4*j+2] += t.z * v;
      acc[4*j+3] += t.w * v;
    }
  }
  #pragma unroll
  for (int o = 0; o < 36; ++o)
    atomicAdd(&xlast[o * HWs + p], acc[o]);
}

// ---------------- K4: smn halves = conv3x3(xlast[4+h*16 .. +16], w_mask), fp64 accum.
// grid (784,2) x 64. h==0 half carries the bias. k_upsample sums halves.
__global__ void k_smn(const float* __restrict__ xlast, const float* __restrict__ wmask,
                      const float* __restrict__ bmask, float* __restrict__ smnh) {
  __shared__ float wm[288];                        // [2 oc][16 ic][9]
  int tid = threadIdx.x;
  int h = blockIdx.y;
  for (int j = tid; j < 288; j += 64) {
    int o = j / 144, r = j - o * 144;              // r = icl*9+tap
    wm[j] = wmask[o * 288 + h * 144 + r];
  }
  __syncthreads();
  int p = blockIdx.x * 64 + tid;
  int y = p / WID, x = p - y * WID;
  double a0 = 0.0, a1 = 0.0;
  for (int icl = 0; icl < 16; ++icl) {
    const float* pl = xlast + (size_t)(4 + h * 16 + icl) * HWs;
    #pragma unroll
    for (int dy = -1; dy <= 1; ++dy) {
      int gy = y + dy;
      if ((unsigned)gy < 224u) {
        #pragma unroll
        for (int dx = -1; dx <= 1; ++dx) {
          int gx = x + dx;
          if ((unsigned)gx < 224u) {
            double v = (double)pl[gy * WID + gx];
            int t = (dy + 1) * 3 + (dx + 1);
            a0 += (double)wm[icl * 9 + t] * v;
            a1 += (double)wm[144 + icl * 9 + t] * v;
          }
        }
      }
    }
  }
  if (h == 0) { a0 += (double)bmask[0]; a1 += (double)bmask[1]; }
  smnh[(size_t)(h * 2 + 0) * HWs + p] = (float)a0;
  smnh[(size_t)(h * 2 + 1) * HWs + p] = (float)a1;
}

// ---------------- K5: 2x bilinear upsample (jax.image.resize 'linear') + mask compare
__global__ void k_upsample(const float* __restrict__ xlast, const float* __restrict__ smnh,
                           const float* __restrict__ smask, float* __restrict__ out) {
  int q = blockIdx.x * 256 + threadIdx.x;          // 784*256 == 200704 exact
  int oy = q / 448, ox = q - oy * 448;
  int ky = oy >> 1, kx = ox >> 1;
  int r0, r1, c0, c1; float wy0, wy1, wx0, wx1;
  if (oy & 1) { r0 = ky; r1 = (ky < 223) ? ky + 1 : 223; wy0 = 0.75f; wy1 = 0.25f; }
  else        { r0 = (ky > 0) ? ky - 1 : 0; r1 = ky;     wy0 = 0.25f; wy1 = 0.75f; }
  if (ox & 1) { c0 = kx; c1 = (kx < 223) ? kx + 1 : 223; wx0 = 0.75f; wx1 = 0.25f; }
  else        { c0 = (kx > 0) ? kx - 1 : 0; c1 = kx;     wx0 = 0.25f; wx1 = 0.75f; }
  float w00 = wy0 * wx0, w01 = wy0 * wx1, w10 = wy1 * wx0, w11 = wy1 * wx1;
  int i00 = r0 * WID + c0, i01 = r0 * WID + c1, i10 = r1 * WID + c0, i11 = r1 * WID + c1;
  for (int ch = 0; ch < 36; ++ch) {
    const float* pl = xlast + (size_t)ch * HWs;
    out[(size_t)ch * OHW + q] = w00 * pl[i00] + w01 * pl[i01]
                              + w10 * pl[i10] + w11 * pl[i11];
  }
  const float* sa0 = smnh;                 // oc0 half0 (+bias)
  const float* sa1 = smnh + HWs;           // oc1 half0 (+bias)
  const float* sb0 = smnh + 2 * HWs;       // oc0 half1
  const float* sb1 = smnh + 3 * HWs;       // oc1 half1
  double s0 = (double)w00 * ((double)sa0[i00] + (double)sb0[i00])
            + (double)w01 * ((double)sa0[i01] + (double)sb0[i01])
            + (double)w10 * ((double)sa0[i10] + (double)sb0[i10])
            + (double)w11 * ((double)sa0[i11] + (double)sb0[i11]);
  double s1 = (double)w00 * ((double)sa1[i00] + (double)sb1[i00])
            + (double)w01 * ((double)sa1[i01] + (double)sb1[i01])
            + (double)w10 * ((double)sa1[i10] + (double)sb1[i10])
            + (double)w11 * ((double)sa1[i11] + (double)sb1[i11]);
  float mu = smask[ky * WID + kx];
  out[36 * OHW + q] = (s0 > s1) ? mu : 0.f;
}

extern "C" void kernel_launch(void* const* d_in, const int* in_sizes, int n_in,
                              void* d_out, int out_size, void* d_ws, size_t ws_size,
                              hipStream_t stream) {
  const float* feat0   = (const float*)d_in[0];
  const float* feat1   = (const float*)d_in[1];
  const float* featd   = (const float*)d_in[2];
  const float* flow    = (const float*)d_in[3];
  const float* smask   = (const float*)d_in[4];
  const float* w_head  = (const float*)d_in[5];
  const float* a_head  = (const float*)d_in[6];
  const float* w_blk   = (const float*)d_in[7];
  const float* a_blk   = (const float*)d_in[8];
  const float* w_last  = (const float*)d_in[9];
  const float* b_last  = (const float*)d_in[10];
  const float* w_mask  = (const float*)d_in[11];
  const float* b_mask  = (const float*)d_in[12];

  // ws layout: act0/act1 + partials pA/pB/pC + xlast + smnh(4) + wt (~111 MB)
  float* act0  = (float*)d_ws;            // 100 planes
  float* act1  = act0 + 100 * HWs;        // 100 planes
  float* pA    = act1 + 100 * HWs;        // 100 planes
  float* pB    = pA   + 100 * HWs;        // 100 planes
  float* pC    = pB   + 100 * HWs;        // 100 planes
  float* xlast = pC   + 100 * HWs;        // 36 planes
  float* smnh  = xlast + 36 * HWs;        // 4 planes
  float* wt    = smnh + 4 * HWs;          // 5*90000 floats

  k_wt<<<dim3(352, 5), 256, 0, stream>>>(w_head, w_blk, wt);
  k_binit<<<dim3(196, 36), 256, 0, stream>>>(b_last, xlast);
  k_warp<<<dim3(196, 4), 256, 0, stream>>>(feat0, feat1, featd, flow, act0);

  dim3 cgrid(14, 45, 3);
  dim3 pgrid(784, 4);
  // head: act0 -> partials -> act1, einsum slice 0
  k_conv<<<cgrid, 256, 0, stream>>>(act0, wt, pA);
  k_post<<<pgrid, 64, 0, stream>>>(pA, pB, pC, a_head, smask, w_last,
                                   act1, xlast, 0);
  // blocks: ping-pong act1 <-> act0
  float* src = act1; float* dst = act0;
  for (int l = 0; l < 4; ++l) {
    k_conv<<<cgrid, 256, 0, stream>>>(src, wt + (l + 1) * 90000, pA);
    k_post<<<pgrid, 64, 0, stream>>>(pA, pB, pC, a_blk + l * 100, smask, w_last,
                                     dst, xlast, (l + 1) * 100);
    float* t = src; src = dst; dst = t;
  }

  k_smn<<<dim3(784, 2), 64, 0, stream>>>(xlast, w_mask, b_mask, smnh);
  k_upsample<<<784, 256, 0, stream>>>(xlast, smnh, smask, (float*)d_out);
}